// Round 3
// baseline (69.270 us; speedup 1.0000x reference)
//
#include <hip/hip_runtime.h>

// MeanAggregator: 4 fused gather outputs.
//   out0 = mean_k features[neigh_idx[b,k]]          [B, D]
//   out1 = mean_k features[perm[neigh_idx[b,k]]]    [B, D]
//   out2 = features[nodes[b]]                       [B, D]
//   out3 = features[perm[nodes[b]]]                 [B, D]
// B=16384, K=10, D=256, features [100000, 256] f32.
//
// R3: non-temporal output stores via clang ext_vector float4 (HIP's
// float4 class is rejected by __builtin_nontemporal_store). Output
// (64 MB/replay) is write-once, never re-read; regular stores were
// evicting the 102 MB feature table from L3 (FETCH 182 MB vs ~104 MB
// compulsory).

typedef float f32x4 __attribute__((ext_vector_type(4)));

constexpr int BATCH    = 16384;
constexpr int K_SAMPLE = 10;
constexpr int D_FEAT   = 256;
constexpr int ROWS_PER_BLOCK = 4;   // one wave (64 lanes) per batch row

__global__ __launch_bounds__(256)
void mean_agg_kernel(const float* __restrict__ features,
                     const int*   __restrict__ neigh_idx,
                     const int*   __restrict__ nodes,
                     const int*   __restrict__ perm,
                     float*       __restrict__ out)
{
    const int wid  = threadIdx.x >> 6;          // wave id within block
    const int lane = threadIdx.x & 63;
    const int b    = blockIdx.x * ROWS_PER_BLOCK + wid;
    if (b >= BATCH) return;
    const int d = lane * 4;                     // this lane's float4 column

    // ---- skip (self) gathers: issue the 3-deep chain (nodes->perm->row)
    //      FIRST so it overlaps the neighbor k-loop ----
    const int n  = nodes[b];                            // wave-uniform
    const int pn = perm[n];
    const f32x4 o2 = *reinterpret_cast<const f32x4*>(
        &features[(size_t)n  * D_FEAT + d]);
    const f32x4 o3 = *reinterpret_cast<const f32x4*>(
        &features[(size_t)pn * D_FEAT + d]);

    // ---- neighbor means (plain + shuffled) ----
    f32x4 acc  = {0.f, 0.f, 0.f, 0.f};
    f32x4 accs = {0.f, 0.f, 0.f, 0.f};

    #pragma unroll
    for (int k = 0; k < K_SAMPLE; ++k) {
        const int idx  = neigh_idx[b * K_SAMPLE + k];   // wave-uniform
        const int pidx = perm[idx];                     // wave-uniform
        const f32x4 f  = *reinterpret_cast<const f32x4*>(
            &features[(size_t)idx  * D_FEAT + d]);
        const f32x4 fs = *reinterpret_cast<const f32x4*>(
            &features[(size_t)pidx * D_FEAT + d]);
        acc  += f;
        accs += fs;
    }

    const float inv = 1.0f / (float)K_SAMPLE;
    const f32x4 o0 = acc  * inv;
    const f32x4 o1 = accs * inv;

    // ---- stores: outputs concatenated flat in return order.
    //      Non-temporal: written once, never re-read -> don't pollute L2/L3.
    const size_t row = (size_t)b * D_FEAT + d;
    const size_t sec = (size_t)BATCH * D_FEAT;
    __builtin_nontemporal_store(o0, reinterpret_cast<f32x4*>(&out[row]          ));
    __builtin_nontemporal_store(o1, reinterpret_cast<f32x4*>(&out[row +     sec]));
    __builtin_nontemporal_store(o2, reinterpret_cast<f32x4*>(&out[row + 2 * sec]));
    __builtin_nontemporal_store(o3, reinterpret_cast<f32x4*>(&out[row + 3 * sec]));
}

extern "C" void kernel_launch(void* const* d_in, const int* in_sizes, int n_in,
                              void* d_out, int out_size, void* d_ws, size_t ws_size,
                              hipStream_t stream) {
    const float* features  = (const float*)d_in[0];
    const int*   neigh_idx = (const int*)  d_in[1];
    const int*   nodes     = (const int*)  d_in[2];
    const int*   perm      = (const int*)  d_in[3];
    float*       out       = (float*)d_out;

    const int grid = BATCH / ROWS_PER_BLOCK;   // 4096 blocks x 256 threads
    mean_agg_kernel<<<grid, 256, 0, stream>>>(features, neigh_idx, nodes, perm, out);
}

// Round 4
// 59.805 us; speedup vs baseline: 1.1583x; 1.1583x over previous
//
#include <hip/hip_runtime.h>

// MeanAggregator: 4 fused gather outputs.
//   out0 = mean_k features[neigh_idx[b,k]]          [B, D]
//   out1 = mean_k features[perm[neigh_idx[b,k]]]    [B, D]
//   out2 = features[nodes[b]]                       [B, D]
//   out3 = features[perm[nodes[b]]]                 [B, D]
// B=16384, K=10, D=256, features [100000, 256] f32.
//
// R4: XCD-affine D-slicing. The kernel is bound by L2-miss traffic
// (410 MB @ 5.94 TB/s ~= the 6.3 TB/s fabric ceiling); random rows over
// the 102 MB table give ~4% L2 hit. Split D into 8 slices of 32 dims,
// slice = blockIdx%8 -> (round-robin dispatch) slice s lives on XCD s,
// so each XCD's L2 only sees its 12.8 MB sub-table -> ~30% hit on
// re-reads -> fewer L2-miss bytes.

typedef float f32x4 __attribute__((ext_vector_type(4)));

constexpr int BATCH    = 16384;
constexpr int K_SAMPLE = 10;
constexpr int D_FEAT   = 256;
constexpr int SLICES   = 8;          // 32 dims (128 B) per slice
constexpr int SLICE_D  = D_FEAT / SLICES;           // 32 floats
constexpr int CHUNK    = 32;         // batch rows per block
constexpr int THREADS  = 256;        // 8 threads per row-slice x 32 rows

__global__ __launch_bounds__(THREADS)
void mean_agg_kernel(const float* __restrict__ features,
                     const int*   __restrict__ neigh_idx,
                     const int*   __restrict__ nodes,
                     const int*   __restrict__ perm,
                     float*       __restrict__ out)
{
    const int slice = blockIdx.x & (SLICES - 1);    // -> XCD id (round-robin)
    const int chunk = blockIdx.x >> 3;

    const int t     = threadIdx.x;
    const int g     = t >> 3;                       // row-in-chunk 0..31
    const int lane8 = t & 7;                        // float4 column in slice

    const int b = chunk * CHUNK + g;
    const int d = slice * SLICE_D + lane8 * 4;

    // ---- skip (self) gathers first: 3-deep chain overlaps the k-loop ----
    const int n  = nodes[b];
    const int pn = perm[n];
    const f32x4 o2 = *reinterpret_cast<const f32x4*>(
        &features[(size_t)n  * D_FEAT + d]);
    const f32x4 o3 = *reinterpret_cast<const f32x4*>(
        &features[(size_t)pn * D_FEAT + d]);

    // ---- neighbor means (plain + shuffled) ----
    f32x4 acc  = {0.f, 0.f, 0.f, 0.f};
    f32x4 accs = {0.f, 0.f, 0.f, 0.f};

    #pragma unroll
    for (int k = 0; k < K_SAMPLE; ++k) {
        const int idx  = neigh_idx[b * K_SAMPLE + k];
        const int pidx = perm[idx];
        const f32x4 f  = *reinterpret_cast<const f32x4*>(
            &features[(size_t)idx  * D_FEAT + d]);
        const f32x4 fs = *reinterpret_cast<const f32x4*>(
            &features[(size_t)pidx * D_FEAT + d]);
        acc  += f;
        accs += fs;
    }

    const float inv = 1.0f / (float)K_SAMPLE;
    const f32x4 o0 = acc  * inv;
    const f32x4 o1 = accs * inv;

    // ---- stores: outputs concatenated flat in return order ----
    const size_t row = (size_t)b * D_FEAT + d;
    const size_t sec = (size_t)BATCH * D_FEAT;
    __builtin_nontemporal_store(o0, reinterpret_cast<f32x4*>(&out[row]          ));
    __builtin_nontemporal_store(o1, reinterpret_cast<f32x4*>(&out[row +     sec]));
    __builtin_nontemporal_store(o2, reinterpret_cast<f32x4*>(&out[row + 2 * sec]));
    __builtin_nontemporal_store(o3, reinterpret_cast<f32x4*>(&out[row + 3 * sec]));
}

extern "C" void kernel_launch(void* const* d_in, const int* in_sizes, int n_in,
                              void* d_out, int out_size, void* d_ws, size_t ws_size,
                              hipStream_t stream) {
    const float* features  = (const float*)d_in[0];
    const int*   neigh_idx = (const int*)  d_in[1];
    const int*   nodes     = (const int*)  d_in[2];
    const int*   perm      = (const int*)  d_in[3];
    float*       out       = (float*)d_out;

    const int grid = (BATCH / CHUNK) * SLICES;      // 512 chunks x 8 slices = 4096
    mean_agg_kernel<<<grid, THREADS, 0, stream>>>(features, neigh_idx, nodes, perm, out);
}